// Round 3
// baseline (906.733 us; speedup 1.0000x reference)
//
#include <hip/hip_runtime.h>
#include <hip/hip_bf16.h>
#include <hip/hip_fp16.h>

#define B_   128
#define C_   2048
#define S_   196
#define HID_ 1024
#define T_   20
#define M_   (B_ * S_)   // 25088 = 98 * 256 flattened rows

typedef __attribute__((ext_vector_type(8))) short s16x8;   // 8 bf16 (4 VGPRs)
typedef __attribute__((ext_vector_type(4))) float f32x4_t; // MFMA 16x16 acc
typedef __attribute__((ext_vector_type(4))) unsigned short us4;

__device__ __forceinline__ float fast_tanh(float x) {
  float e = __expf(2.f * x);
  return 1.f - 2.f / (e + 1.f);
}
__device__ __forceinline__ unsigned short f2bf(float x) {
  __hip_bfloat16 h = __float2bfloat16(x);
  return *reinterpret_cast<unsigned short*>(&h);
}
// async 16B global->LDS (width=16). LDS dest is wave-uniform base + lane*16,
// so the LDS slot index must be linear in lane — staging loops guarantee it.
__device__ __forceinline__ void gl_lds16(const short* g, short* l) {
  __builtin_amdgcn_global_load_lds(
      (const __attribute__((address_space(1))) void*)g,
      (__attribute__((address_space(3))) void*)l, 16, 0, 0);
}

// ---------------- fp32 -> bf16 weight convert (n % 4 == 0) ----------------
__global__ void cvt_k(const float* __restrict__ in, __hip_bfloat16* __restrict__ out, int n) {
  int i = (blockIdx.x * 256 + threadIdx.x) * 4;
  if (i >= n) return;
  float4 v = *(const float4*)(in + i);
  out[i + 0] = __float2bfloat16(v.x);
  out[i + 1] = __float2bfloat16(v.y);
  out[i + 2] = __float2bfloat16(v.z);
  out[i + 3] = __float2bfloat16(v.w);
}

// ---------------- v_i [b,c,s] fp32 -> viT [b,s,c] bf16 (vectorized) ----------------
__global__ void transpose_k(const float* __restrict__ src, __hip_bfloat16* __restrict__ dst) {
  __shared__ float tile[32][65];               // [s][c], stride 65 -> 2-way max (free)
  int b  = blockIdx.z;
  int c0 = blockIdx.x * 64;
  int s0 = blockIdx.y * 32;
  int t  = threadIdx.x;
  int cl = t >> 3, sq = t & 7;                 // load: 4 s per lane
  const float* sp = src + ((size_t)b * C_ + c0) * S_ + s0;
  #pragma unroll
  for (int p = 0; p < 2; p++) {
    int c = cl + p * 32;
    int s = sq * 4;
    if (s0 + s < S_) {
      float4 v = *(const float4*)(sp + (size_t)c * S_ + s);
      tile[s + 0][c] = v.x; tile[s + 1][c] = v.y;
      tile[s + 2][c] = v.z; tile[s + 3][c] = v.w;
    }
  }
  __syncthreads();
  int sl = t >> 4, cq = t & 15;                // store: 4 c per lane (8B)
  #pragma unroll
  for (int p = 0; p < 2; p++) {
    int s = sl + p * 16;
    if (s0 + s < S_) {
      us4 v;
      v.x = f2bf(tile[s][cq * 4 + 0]); v.y = f2bf(tile[s][cq * 4 + 1]);
      v.z = f2bf(tile[s][cq * 4 + 2]); v.w = f2bf(tile[s][cq * 4 + 3]);
      *(us4*)(dst + ((size_t)b * S_ + s0 + s) * C_ + c0 + cq * 4) = v;
    }
  }
}

// ---------------- u[b,h] = mean_t v_q[b,t,h] ----------------
__global__ void umean_k(const float* __restrict__ vq, float* __restrict__ u) {
  int b = blockIdx.y;
  int h = blockIdx.x * 256 + threadIdx.x;
  const float* p = vq + (size_t)b * T_ * HID_ + h;
  float s = 0.f;
  #pragma unroll
  for (int t = 0; t < T_; t++) s += p[t * HID_];
  u[(size_t)b * HID_ + h] = s * (1.f / T_);
}

// ---------------- vqt[b,k] = sum_h u[b,h]*w_u[k,h] + b_u[k] ----------------
__global__ void vqt_k(const float* __restrict__ u, const float* __restrict__ wu,
                      const float* __restrict__ bu, float* __restrict__ out) {
  __shared__ float us[32][64];
  __shared__ float ws[64][65];
  int k0 = blockIdx.x * 64, b0 = blockIdx.y * 32;
  int tid = threadIdx.x;
  int kl = tid & 63, bg = tid >> 6;
  float acc[8];
  #pragma unroll
  for (int j = 0; j < 8; j++) acc[j] = 0.f;
  for (int h0 = 0; h0 < HID_; h0 += 64) {
    __syncthreads();
    for (int idx = tid; idx < 32 * 16; idx += 256) {
      int bi = idx >> 4, jj = (idx & 15) * 4;
      *(float4*)&us[bi][jj] = *(const float4*)&u[(size_t)(b0 + bi) * HID_ + h0 + jj];
    }
    for (int idx = tid; idx < 64 * 16; idx += 256) {
      int ki = idx >> 4, jj = (idx & 15) * 4;
      float4 v = *(const float4*)&wu[(size_t)(k0 + ki) * HID_ + h0 + jj];
      ws[ki][jj] = v.x; ws[ki][jj + 1] = v.y; ws[ki][jj + 2] = v.z; ws[ki][jj + 3] = v.w;
    }
    __syncthreads();
    #pragma unroll 8
    for (int h = 0; h < 64; h++) {
      float wv = ws[kl][h];
      #pragma unroll
      for (int j = 0; j < 8; j++) acc[j] += wv * us[bg * 8 + j][h];
    }
  }
  #pragma unroll
  for (int j = 0; j < 8; j++)
    out[(size_t)(b0 + bg * 8 + j) * HID_ + k0 + kl] = acc[j] + bu[k0 + kl];
}

// ---------------- main GEMM (m201 geometry, flattened M) ----------------
// out[m,n] = sum_k A[m,k] * W[n,k], M = 25088 (= B*S flattened), N = 1024.
// BM=BN=256, BK=64, 512 threads = 8 waves (2M x 4N), per-wave 128x64,
// acc 8x4 f32x4 = 128 VGPR. LDS 128 KB (A/B double-buffered) -> 1 block/CU.
// LDS layout: row * 8 chunk-slots (16B = 8 bf16 each); slot holds global k-chunk
// q = slot ^ (row&7) -> ds_read_b128 fragment reads land 2-way bank alias (free);
// staging is linear in chunk index (global_load_lds requirement).
// Pipeline: 2 buffers, prefetch distance 1, counted vmcnt(8) (uniform: every
// thread issues exactly 8 gl_lds per stage). No vmcnt(0) drain in main loop;
// issue->consume gap = one full compute phase (~2500 cyc) > HBM latency.
// Grid 392 = 98 m-tiles x 4 n-tiles = 8 XCD x 49, bijective XCD swizzle.
// MODE 0: out = bf16 tanh(acc + bias[n])            (l1 layer)
// MODE 1: out = fp16 tanh(acc + vqt[b(m), n])       (hop h_a; b = m/196 by magic)
template<int KDIM, int MODE>
__global__ __launch_bounds__(512, 2)
void gemm2_k(const __hip_bfloat16* __restrict__ Asrc,
             const __hip_bfloat16* __restrict__ Bw,
             const float* __restrict__ aux,
             void* __restrict__ outp) {
  constexpr int NT = KDIM / 64;
  __shared__ short a_lds[2][256 * 8 * 8];      // [buf][row*8 + slot][8 bf16]
  __shared__ short b_lds[2][256 * 8 * 8];

  // XCD swizzle: 392 = 8 * 49; XCD x gets contiguous wg chunk (A-tile L2 reuse)
  const int wg  = (blockIdx.x & 7) * 49 + (blockIdx.x >> 3);
  const int m0  = (wg >> 2) * 256;             // 98 m-tiles
  const int n0  = (wg & 3) * 256;              // 4 n-tiles
  const int tid  = threadIdx.x;
  const int wid  = tid >> 6;
  const int wr   = wid >> 2;                   // 0..1  (M)
  const int wc   = wid & 3;                    // 0..3  (N)
  const int lane = tid & 63;
  const int ln   = lane & 15;
  const int quad = lane >> 4;

  const short* Ab = (const short*)Asrc + (size_t)m0 * KDIM;
  const short* Bb = (const short*)Bw + (size_t)n0 * KDIM;

  f32x4_t acc[8][4] = {};

  // stage K-tile at k0 into buffer bb: 8 gl_lds per thread (4 A + 4 B), uniform.
  auto stage = [&](int bb, int k0) {
    #pragma unroll
    for (int p = 0; p < 4; p++) {
      int i = tid + p * 512;
      int row = i >> 3;
      int q = (i & 7) ^ (row & 7);
      gl_lds16(Ab + (size_t)row * KDIM + k0 + q * 8, &a_lds[bb][i * 8]);
    }
    #pragma unroll
    for (int p = 0; p < 4; p++) {
      int i = tid + p * 512;
      int row = i >> 3;
      int q = (i & 7) ^ (row & 7);
      gl_lds16(Bb + (size_t)row * KDIM + k0 + q * 8, &b_lds[bb][i * 8]);
    }
  };

  // one K-step (BK=64 = 2 MFMA k-halves): 24 ds_read_b128 + 64 MFMA per wave
  auto compute = [&](int bb) {
    s16x8 bf[4][2];
    #pragma unroll
    for (int ns = 0; ns < 4; ns++) {
      int row = wc * 64 + ns * 16 + ln;
      #pragma unroll
      for (int kh = 0; kh < 2; kh++) {
        int q = kh * 4 + quad;
        bf[ns][kh] = *(s16x8*)&b_lds[bb][(row * 8 + (q ^ (row & 7))) * 8];
      }
    }
    __builtin_amdgcn_s_setprio(1);
    #pragma unroll
    for (int ms = 0; ms < 8; ms++) {
      int row = wr * 128 + ms * 16 + ln;
      s16x8 a0 = *(s16x8*)&a_lds[bb][(row * 8 + ((0 + quad) ^ (row & 7))) * 8];
      s16x8 a1 = *(s16x8*)&a_lds[bb][(row * 8 + ((4 + quad) ^ (row & 7))) * 8];
      #pragma unroll
      for (int ns = 0; ns < 4; ns++)
        acc[ms][ns] = __builtin_amdgcn_mfma_f32_16x16x32_bf16(a0, bf[ns][0], acc[ms][ns], 0, 0, 0);
      #pragma unroll
      for (int ns = 0; ns < 4; ns++)
        acc[ms][ns] = __builtin_amdgcn_mfma_f32_16x16x32_bf16(a1, bf[ns][1], acc[ms][ns], 0, 0, 0);
    }
    __builtin_amdgcn_s_setprio(0);
  };

  stage(0, 0);
  stage(1, 64);                                // 16 loads outstanding
  int cur = 0;
  for (int t = 0; t < NT - 1; ++t) {
    asm volatile("s_waitcnt vmcnt(8)" ::: "memory");  // tile t landed; t+1 in flight
    __builtin_amdgcn_s_barrier();              // all waves' tile-t writes visible
    __builtin_amdgcn_sched_barrier(0);
    compute(cur);
    __builtin_amdgcn_sched_barrier(0);
    __builtin_amdgcn_s_barrier();              // reads of buf[cur] retired
    __builtin_amdgcn_sched_barrier(0);
    if (t + 2 < NT) stage(cur, (t + 2) * 64);  // overwrite with tile t+2
    cur ^= 1;
  }
  asm volatile("s_waitcnt vmcnt(0)" ::: "memory");
  __builtin_amdgcn_s_barrier();
  __builtin_amdgcn_sched_barrier(0);
  compute(cur);

  // epilogue. C/D: col = ln, row = quad*4 + r (within 16x16 fragment)
  const int colb = n0 + wc * 64;
  if (MODE == 0) {
    __hip_bfloat16* out = (__hip_bfloat16*)outp;
    float bias[4];
    #pragma unroll
    for (int ns = 0; ns < 4; ns++) bias[ns] = aux[colb + ns * 16 + ln];
    #pragma unroll
    for (int ms = 0; ms < 8; ms++) {
      #pragma unroll
      for (int r = 0; r < 4; r++) {
        int row = m0 + wr * 128 + ms * 16 + quad * 4 + r;
        #pragma unroll
        for (int ns = 0; ns < 4; ns++)
          out[(size_t)row * HID_ + colb + ns * 16 + ln] =
              __float2bfloat16(fast_tanh(acc[ms][ns][r] + bias[ns]));
      }
    }
  } else {
    // b = row / 196 exact for row < 25088 via magic (196*85599 - 2^24 = 188;
    // 188 * 25087 < 2^24). Wave's 128 rows span at most 2 batches.
    __half* out = (__half*)outp;
    const unsigned rf = (unsigned)(m0 + wr * 128);
    const unsigned bA = (rf * 85599u) >> 24;
    const unsigned bB = ((rf + 127u) * 85599u) >> 24;
    float auxA[4], auxB[4];
    #pragma unroll
    for (int ns = 0; ns < 4; ns++) {
      auxA[ns] = aux[(size_t)bA * HID_ + colb + ns * 16 + ln];
      auxB[ns] = aux[(size_t)bB * HID_ + colb + ns * 16 + ln];
    }
    #pragma unroll
    for (int ms = 0; ms < 8; ms++) {
      #pragma unroll
      for (int r = 0; r < 4; r++) {
        unsigned row = rf + ms * 16 + quad * 4 + r;
        unsigned bb = (row * 85599u) >> 24;
        #pragma unroll
        for (int ns = 0; ns < 4; ns++) {
          float vq = (bb == bA) ? auxA[ns] : auxB[ns];
          out[(size_t)row * HID_ + colb + ns * 16 + ln] =
              __float2half(fast_tanh(acc[ms][ns][r] + vq));
        }
      }
    }
  }
}

// ---------------- softmax-reduce: u[b,n] += sum_s softmax_s(h_a)[s,n]*vi[b,s,n] ----
// h_a = tanh(...) is bounded in (-1,1) => exp(h) in (0.37, 2.72): no max tracking
// needed (shift-invariant softmax). Two independent fma chains for ILP.
__global__ __launch_bounds__(256)
void sr_k(const __half* __restrict__ ha, const __hip_bfloat16* __restrict__ vi,
          float* __restrict__ u) {
  int b = blockIdx.y;
  int n = blockIdx.x * 256 + threadIdx.x;
  const __half* hp = ha + (size_t)b * S_ * HID_ + n;
  const __hip_bfloat16* vp = vi + (size_t)b * S_ * HID_ + n;
  float d0 = 0.f, w0 = 0.f, d1 = 0.f, w1 = 0.f;
  #pragma unroll 4
  for (int s = 0; s < S_; s += 2) {
    float h0 = __half2float(hp[(size_t)s * HID_]);
    float h1 = __half2float(hp[(size_t)(s + 1) * HID_]);
    float v0 = __bfloat162float(vp[(size_t)s * HID_]);
    float v1 = __bfloat162float(vp[(size_t)(s + 1) * HID_]);
    float e0 = __expf(h0);
    float e1 = __expf(h1);
    d0 += e0; w0 += e0 * v0;
    d1 += e1; w1 += e1 * v1;
  }
  u[(size_t)b * HID_ + n] += (w0 + w1) / (d0 + d1);
}

extern "C" void kernel_launch(void* const* d_in, const int* in_sizes, int n_in,
                              void* d_out, int out_size, void* d_ws, size_t ws_size,
                              hipStream_t stream) {
  const float* v_i   = (const float*)d_in[0];
  const float* v_q   = (const float*)d_in[1];
  const float* l1_w  = (const float*)d_in[2];
  const float* l1_b  = (const float*)d_in[3];
  const float* w_vi0 = (const float*)d_in[4];
  const float* w_u0  = (const float*)d_in[5];
  const float* b_u0  = (const float*)d_in[6];
  const float* w_vi1 = (const float*)d_in[7];
  const float* w_u1  = (const float*)d_in[8];
  const float* b_u1  = (const float*)d_in[9];
  float* u = (float*)d_out;

  __hip_bfloat16* viT  = (__hip_bfloat16*)d_ws;                    // [M][C]
  __hip_bfloat16* vi   = viT + (size_t)M_ * C_;                    // [M][HID]
  float*          vqt  = (float*)(vi + (size_t)M_ * HID_);         // [B][HID]
  __hip_bfloat16* l1wb = (__hip_bfloat16*)(vqt + (size_t)B_ * HID_);
  __hip_bfloat16* wv0b = l1wb + (size_t)HID_ * C_;
  __hip_bfloat16* wv1b = wv0b + (size_t)HID_ * HID_;
  __half*         ha   = (__half*)viT;         // overlays viT (dead after l1 GEMM)

  cvt_k<<<dim3((HID_ * C_) / 1024), 256, 0, stream>>>(l1_w, l1wb, HID_ * C_);
  cvt_k<<<dim3((HID_ * HID_) / 1024), 256, 0, stream>>>(w_vi0, wv0b, HID_ * HID_);
  cvt_k<<<dim3((HID_ * HID_) / 1024), 256, 0, stream>>>(w_vi1, wv1b, HID_ * HID_);
  transpose_k<<<dim3(C_ / 64, 7, B_), 256, 0, stream>>>(v_i, viT);
  umean_k<<<dim3(HID_ / 256, B_), 256, 0, stream>>>(v_q, u);

  gemm2_k<C_, 0><<<dim3(392), 512, 0, stream>>>(viT, l1wb, l1_b, vi);

  vqt_k<<<dim3(16, 4), 256, 0, stream>>>(u, w_u0, b_u0, vqt);
  gemm2_k<HID_, 1><<<dim3(392), 512, 0, stream>>>(vi, wv0b, vqt, ha);
  sr_k<<<dim3(4, B_), 256, 0, stream>>>(ha, vi, u);

  vqt_k<<<dim3(16, 4), 256, 0, stream>>>(u, w_u1, b_u1, vqt);
  gemm2_k<HID_, 1><<<dim3(392), 512, 0, stream>>>(vi, wv1b, vqt, ha);
  sr_k<<<dim3(4, B_), 256, 0, stream>>>(ha, vi, u);
}